// Round 5
// baseline (638.872 us; speedup 1.0000x reference)
//
#include <hip/hip_runtime.h>
#include <cstdint>

#define IROWS 50000
#define DIM   512
#define KTOT  1024
#define THREADS 512
#define ROWS_PER_BLK 128
#define NBLK ((IROWS + ROWS_PER_BLK - 1) / ROWS_PER_BLK)   // 391
#define NCHUNK 16
#define CK 64             // k per chunk -> B chunk = 512*64*2B = 64 KB LDS

typedef __bf16 bf16x8 __attribute__((ext_vector_type(8)));
typedef float  f32x4  __attribute__((ext_vector_type(4)));

__device__ __forceinline__ uint16_t f2bf(float f) {
  uint32_t u = __float_as_uint(f);
  u += 0x7fffu + ((u >> 16) & 1u);   // round-to-nearest-even (inputs finite)
  return (uint16_t)(u >> 16);
}

// Build Bt[n][k] (bf16, row-major [512][1024]) = concat_k( alpha*delta_img, beta*delta_txt )^T
__global__ __launch_bounds__(256) void prep_bt(const float* __restrict__ dimg,
                                               const float* __restrict__ dtxt,
                                               const float* __restrict__ pa,
                                               const float* __restrict__ pb,
                                               uint16_t* __restrict__ bt) {
  __shared__ uint16_t tile[64][80];
  int bid = blockIdx.x;              // 128 blocks: 16 k-tiles x 8 n-tiles
  int kt = bid >> 3, nt = bid & 7;
  int k0 = kt * 64, n0 = nt * 64;
  const float* src; float sc;
  if (k0 < 512) { src = dimg + (size_t)k0 * 512;         sc = pa[0]; }
  else          { src = dtxt + (size_t)(k0 - 512) * 512; sc = pb[0]; }
  int t = threadIdx.x;
  int c4 = (t & 15) * 4, r = t >> 4;
  for (int rr = r; rr < 64; rr += 16) {
    float4 v = *(const float4*)(src + (size_t)rr * 512 + n0 + c4);
    tile[c4 + 0][rr] = f2bf(v.x * sc);
    tile[c4 + 1][rr] = f2bf(v.y * sc);
    tile[c4 + 2][rr] = f2bf(v.z * sc);
    tile[c4 + 3][rr] = f2bf(v.w * sc);
  }
  __syncthreads();
  int j = t & 7;
  for (int nn = t >> 3; nn < 64; nn += 32) {
    uint4 val = *(const uint4*)(&tile[nn][j * 8]);
    *(uint4*)(bt + (size_t)(n0 + nn) * KTOT + k0 + j * 8) = val;
  }
}

// 8 waves x (16 rows x 512 cols). B-chunk [512][64k] (64 KB, swizzled) in LDS,
// staged from L2-resident bt per chunk. 2 blocks/CU hide each other's stalls.
__global__ __launch_bounds__(THREADS, 4) void fused_main(
    const float* __restrict__ zcf, const float* __restrict__ zimg,
    const float* __restrict__ ztxt, const uint16_t* __restrict__ bt,
    const float* __restrict__ pa, const float* __restrict__ pb,
    const float* __restrict__ lnw, const float* __restrict__ lnb,
    float* __restrict__ out) {
  __shared__ __align__(16) uint4 Bs[512 * 8];   // [n][8 x 16B slot], slot ^= (n&7)

  const int t    = threadIdx.x;
  const int lane = t & 63;
  const int widx = t >> 6;          // 0..7
  const int cl   = lane & 15;
  const int kq   = lane >> 4;       // 0..3
  const int rbase = blockIdx.x * ROWS_PER_BLK + widx * 16;
  const int arow  = min(rbase + cl, IROWS - 1);
  const size_t arow512 = (size_t)arow * DIM;

  f32x4 acc[32];
  const f32x4 zero = {0.f, 0.f, 0.f, 0.f};
#pragma unroll
  for (int nf = 0; nf < 32; ++nf) acc[nf] = zero;

  float4 Araw[4];                    // next-chunk A: 2 kfrags x 32B
  auto aload = [&](int c) {
    const float* base = (c < 8) ? (zimg + arow512 + c * CK)
                                : (ztxt + arow512 + (c - 8) * CK);
#pragma unroll
    for (int kf = 0; kf < 2; ++kf) {
      Araw[kf * 2 + 0] = *(const float4*)(base + kf * 32 + kq * 8);
      Araw[kf * 2 + 1] = *(const float4*)(base + kf * 32 + kq * 8 + 4);
    }
  };
  auto pack8 = [&](float4 a0, float4 a1) -> bf16x8 {
    union { uint32_t u[4]; bf16x8 v; } c;
    c.u[0] = (uint32_t)f2bf(a0.x) | ((uint32_t)f2bf(a0.y) << 16);
    c.u[1] = (uint32_t)f2bf(a0.z) | ((uint32_t)f2bf(a0.w) << 16);
    c.u[2] = (uint32_t)f2bf(a1.x) | ((uint32_t)f2bf(a1.y) << 16);
    c.u[3] = (uint32_t)f2bf(a1.z) | ((uint32_t)f2bf(a1.w) << 16);
    return c.v;
  };

  aload(0);

#pragma unroll 1
  for (int c = 0; c < NCHUNK; ++c) {
    const int k0 = c * CK;
    __syncthreads();                 // all waves done reading previous chunk
    // stage B chunk: [512 n][64 k] bf16, coalesced from L2, swizzled into LDS
#pragma unroll 4
    for (int p = 0; p < 8; ++p) {
      int n = p * 64 + (t >> 3);
      int i = t & 7;
      uint4 v = *(const uint4*)(bt + (size_t)n * KTOT + k0 + i * 8);
      Bs[n * 8 + (i ^ (n & 7))] = v;
    }
    __syncthreads();

    bf16x8 af[2];
#pragma unroll
    for (int kf = 0; kf < 2; ++kf) af[kf] = pack8(Araw[kf * 2], Araw[kf * 2 + 1]);
    if (c + 1 < NCHUNK) aload(c + 1);   // HBM prefetch flies across next barrier

#pragma unroll
    for (int kf = 0; kf < 2; ++kf)
#pragma unroll
      for (int nf = 0; nf < 32; ++nf) {
        int n = nf * 16 + cl;
        bf16x8 bf = *(const bf16x8*)&Bs[n * 8 + ((kf * 4 + kq) ^ (n & 7))];
        acc[nf] = __builtin_amdgcn_mfma_f32_16x16x32_bf16(af[kf], bf, acc[nf], 0, 0, 0);
      }
  }

  // ---- epilogue (wave-local): + wcf*z_cf, LayerNorm, L2 normalize ----
  const float wcf = 1.0f - pa[0] - pb[0];

  // C layout: col = nf*16 + cl, row = rbase + kq*4 + reg
#pragma unroll
  for (int nf = 0; nf < 32; ++nf) {
#pragma unroll
    for (int reg = 0; reg < 4; ++reg) {
      int row = rbase + kq * 4 + reg;
      const float* p = zcf + (size_t)min(row, IROWS - 1) * DIM + nf * 16 + cl;
      acc[nf][reg] += wcf * (*p);
    }
  }

  float mu[4], rs[4];
#pragma unroll
  for (int reg = 0; reg < 4; ++reg) {
    float s1 = 0.f, s2 = 0.f;
#pragma unroll
    for (int nf = 0; nf < 32; ++nf) { float v = acc[nf][reg]; s1 += v; s2 += v * v; }
#pragma unroll
    for (int m = 1; m < 16; m <<= 1) { s1 += __shfl_xor(s1, m, 64); s2 += __shfl_xor(s2, m, 64); }
    float mean = s1 * (1.0f / 512.0f);
    mu[reg] = mean;
    rs[reg] = rsqrtf(s2 * (1.0f / 512.0f) - mean * mean + 1e-5f);
  }

  float q[4] = {0.f, 0.f, 0.f, 0.f};
#pragma unroll
  for (int nf = 0; nf < 32; ++nf) {
    float wv = lnw[nf * 16 + cl];
    float bv = lnb[nf * 16 + cl];
#pragma unroll
    for (int reg = 0; reg < 4; ++reg) {
      float y = (acc[nf][reg] - mu[reg]) * rs[reg] * wv + bv;
      acc[nf][reg] = y;
      q[reg] += y * y;
    }
  }
  float rnorm[4];
#pragma unroll
  for (int reg = 0; reg < 4; ++reg) {
    float qq = q[reg];
#pragma unroll
    for (int m = 1; m < 16; m <<= 1) qq += __shfl_xor(qq, m, 64);
    rnorm[reg] = 1.0f / fmaxf(sqrtf(qq), 1e-12f);
  }

#pragma unroll
  for (int reg = 0; reg < 4; ++reg) {
    int row = rbase + kq * 4 + reg;
    if (row < IROWS) {
      float* orow = out + (size_t)row * DIM + cl;
      float sc = rnorm[reg];
#pragma unroll
      for (int nf = 0; nf < 32; ++nf)
        orow[nf * 16] = acc[nf][reg] * sc;
    }
  }
}

extern "C" void kernel_launch(void* const* d_in, const int* in_sizes, int n_in,
                              void* d_out, int out_size, void* d_ws, size_t ws_size,
                              hipStream_t stream) {
  const float* zcf  = (const float*)d_in[0];
  const float* zimg = (const float*)d_in[1];
  const float* ztxt = (const float*)d_in[2];
  const float* dimg = (const float*)d_in[3];
  const float* dtxt = (const float*)d_in[4];
  const float* pa   = (const float*)d_in[5];
  const float* pb   = (const float*)d_in[6];
  const float* lnw  = (const float*)d_in[7];
  const float* lnb  = (const float*)d_in[8];
  uint16_t* bt = (uint16_t*)d_ws;   // 512*1024 bf16 = 1 MB

  hipLaunchKernelGGL(prep_bt, dim3(128), dim3(256), 0, stream, dimg, dtxt, pa, pb, bt);
  hipLaunchKernelGGL(fused_main, dim3(NBLK), dim3(THREADS), 0, stream,
                     zcf, zimg, ztxt, bt, pa, pb, lnw, lnb, (float*)d_out);
}

// Round 6
// 206.471 us; speedup vs baseline: 3.0942x; 3.0942x over previous
//
#include <hip/hip_runtime.h>
#include <cstdint>

#define IROWS 50000
#define DIM   512
#define KTOT  1024
#define THREADS 512
#define ROWS_PER_BLK 64
#define NBLK ((IROWS + ROWS_PER_BLK - 1) / ROWS_PER_BLK)   // 782
#define NCHUNK 16
#define CK 64             // k per chunk -> B chunk = 512*64*2B = 64 KB LDS

typedef __bf16 bf16x8 __attribute__((ext_vector_type(8)));
typedef float  f32x4  __attribute__((ext_vector_type(4)));

__device__ __forceinline__ uint16_t f2bf(float f) {
  uint32_t u = __float_as_uint(f);
  u += 0x7fffu + ((u >> 16) & 1u);   // round-to-nearest-even (inputs finite)
  return (uint16_t)(u >> 16);
}

// Build Bt[n][k] (bf16, row-major [512][1024]) = concat_k( alpha*delta_img, beta*delta_txt )^T
__global__ __launch_bounds__(256) void prep_bt(const float* __restrict__ dimg,
                                               const float* __restrict__ dtxt,
                                               const float* __restrict__ pa,
                                               const float* __restrict__ pb,
                                               uint16_t* __restrict__ bt) {
  __shared__ uint16_t tile[64][80];
  int bid = blockIdx.x;              // 128 blocks: 16 k-tiles x 8 n-tiles
  int kt = bid >> 3, nt = bid & 7;
  int k0 = kt * 64, n0 = nt * 64;
  const float* src; float sc;
  if (k0 < 512) { src = dimg + (size_t)k0 * 512;         sc = pa[0]; }
  else          { src = dtxt + (size_t)(k0 - 512) * 512; sc = pb[0]; }
  int t = threadIdx.x;
  int c4 = (t & 15) * 4, r = t >> 4;
  for (int rr = r; rr < 64; rr += 16) {
    float4 v = *(const float4*)(src + (size_t)rr * 512 + n0 + c4);
    tile[c4 + 0][rr] = f2bf(v.x * sc);
    tile[c4 + 1][rr] = f2bf(v.y * sc);
    tile[c4 + 2][rr] = f2bf(v.z * sc);
    tile[c4 + 3][rr] = f2bf(v.w * sc);
  }
  __syncthreads();
  int j = t & 7;
  for (int nn = t >> 3; nn < 64; nn += 32) {
    uint4 val = *(const uint4*)(&tile[nn][j * 8]);
    *(uint4*)(bt + (size_t)(n0 + nn) * KTOT + k0 + j * 8) = val;
  }
}

// 8 waves = 4 row-groups x 2 col-halves; wave = 16 rows x 256 cols (acc = 64 regs).
// Unified regs/wave ~119 < 128 -> 4 waves/SIMD, 2 blocks/CU (LDS 73.7 KB/block).
__global__ __launch_bounds__(THREADS, 4) void fused_main(
    const float* __restrict__ zcf, const float* __restrict__ zimg,
    const float* __restrict__ ztxt, const uint16_t* __restrict__ bt,
    const float* __restrict__ pa, const float* __restrict__ pb,
    const float* __restrict__ lnw, const float* __restrict__ lnb,
    float* __restrict__ out) {
  __shared__ __align__(16) uint4 Bs[512 * 8];   // [col][8 x 16B k-slot], slot ^= (col&7)
  __shared__ __align__(16) uint4 As[64 * 8];    // [row][8 x 16B k-slot], slot ^= (row&7)
  __shared__ float red1[4][16][2][2];           // [rowgrp][row16][half][{s1,s2}]
  __shared__ float red2[4][16][2];              // [rowgrp][row16][half]

  const int t    = threadIdx.x;
  const int lane = t & 63;
  const int w    = t >> 6;          // 0..7
  const int g    = w >> 1;          // row-group 0..3
  const int h    = w & 1;           // col-half 0..1
  const int cl   = lane & 15;
  const int kq   = lane >> 4;       // 0..3
  const int rbase = blockIdx.x * ROWS_PER_BLK + g * 16;

  f32x4 acc[16];
  const f32x4 zero = {0.f, 0.f, 0.f, 0.f};
#pragma unroll
  for (int nf = 0; nf < 16; ++nf) acc[nf] = zero;

  // staging indices
  const int sr   = t >> 3;                        // 0..63 row (A) / row-stride base (B)
  const int si   = t & 7;                         // 16B slot
  const int agrow = min(blockIdx.x * ROWS_PER_BLK + sr, IROWS - 1);
  const size_t agoff = (size_t)agrow * DIM;

#pragma unroll 1
  for (int c = 0; c < NCHUNK; ++c) {
    const int k0 = c * CK;
    __syncthreads();                 // previous chunk fully consumed
    // ---- stage B chunk [512 col][64 k] bf16 from L2-resident bt ----
#pragma unroll
    for (int p = 0; p < 8; ++p) {
      int n = p * 64 + sr;
      uint4 v = *(const uint4*)(bt + (size_t)n * KTOT + k0 + si * 8);
      Bs[n * 8 + (si ^ (n & 7))] = v;
    }
    // ---- stage A chunk [64 row][64 k] f32->bf16 from HBM ----
    {
      int gk = k0 + si * 8;
      const float* s = (gk < 512) ? (zimg + agoff + gk) : (ztxt + agoff + gk - 512);
      float4 a0 = *(const float4*)(s);
      float4 a1 = *(const float4*)(s + 4);
      uint4 pk;
      pk.x = (uint32_t)f2bf(a0.x) | ((uint32_t)f2bf(a0.y) << 16);
      pk.y = (uint32_t)f2bf(a0.z) | ((uint32_t)f2bf(a0.w) << 16);
      pk.z = (uint32_t)f2bf(a1.x) | ((uint32_t)f2bf(a1.y) << 16);
      pk.w = (uint32_t)f2bf(a1.z) | ((uint32_t)f2bf(a1.w) << 16);
      As[sr * 8 + (si ^ (sr & 7))] = pk;
    }
    __syncthreads();
    // ---- compute: 2 kfrags x 16 nfrags ----
#pragma unroll
    for (int kf = 0; kf < 2; ++kf) {
      int arow16 = g * 16 + cl;
      bf16x8 af = *(const bf16x8*)&As[arow16 * 8 + ((kf * 4 + kq) ^ (arow16 & 7))];
#pragma unroll
      for (int nf = 0; nf < 16; ++nf) {
        int n = h * 256 + nf * 16 + cl;
        bf16x8 bf = *(const bf16x8*)&Bs[n * 8 + ((kf * 4 + kq) ^ (n & 7))];
        acc[nf] = __builtin_amdgcn_mfma_f32_16x16x32_bf16(af, bf, acc[nf], 0, 0, 0);
      }
    }
  }

  // ---- epilogue: + wcf*z_cf, LayerNorm, L2 normalize (cross-half via LDS) ----
  const float wcf = 1.0f - pa[0] - pb[0];

  // C layout: col = h*256 + nf*16 + cl, row = rbase + kq*4 + reg
#pragma unroll
  for (int nf = 0; nf < 16; ++nf) {
#pragma unroll
    for (int reg = 0; reg < 4; ++reg) {
      int row = min(rbase + kq * 4 + reg, IROWS - 1);
      acc[nf][reg] += wcf * zcf[(size_t)row * DIM + h * 256 + nf * 16 + cl];
    }
  }

  // partial sums over this wave's 256 cols, exchange halves through LDS
#pragma unroll
  for (int reg = 0; reg < 4; ++reg) {
    float s1 = 0.f, s2 = 0.f;
#pragma unroll
    for (int nf = 0; nf < 16; ++nf) { float v = acc[nf][reg]; s1 += v; s2 += v * v; }
#pragma unroll
    for (int m = 1; m < 16; m <<= 1) { s1 += __shfl_xor(s1, m, 64); s2 += __shfl_xor(s2, m, 64); }
    if (cl == 0) {
      red1[g][kq * 4 + reg][h][0] = s1;
      red1[g][kq * 4 + reg][h][1] = s2;
    }
  }
  __syncthreads();
  float mu[4], rs[4];
#pragma unroll
  for (int reg = 0; reg < 4; ++reg) {
    int r16 = kq * 4 + reg;
    float s1 = red1[g][r16][0][0] + red1[g][r16][1][0];
    float s2 = red1[g][r16][0][1] + red1[g][r16][1][1];
    float mean = s1 * (1.0f / 512.0f);
    mu[reg] = mean;
    rs[reg] = rsqrtf(s2 * (1.0f / 512.0f) - mean * mean + 1e-5f);
  }

  float q[4] = {0.f, 0.f, 0.f, 0.f};
#pragma unroll
  for (int nf = 0; nf < 16; ++nf) {
    int col = h * 256 + nf * 16 + cl;
    float wv = lnw[col];
    float bv = lnb[col];
#pragma unroll
    for (int reg = 0; reg < 4; ++reg) {
      float y = (acc[nf][reg] - mu[reg]) * rs[reg] * wv + bv;
      acc[nf][reg] = y;
      q[reg] += y * y;
    }
  }
#pragma unroll
  for (int reg = 0; reg < 4; ++reg) {
    float qq = q[reg];
#pragma unroll
    for (int m = 1; m < 16; m <<= 1) qq += __shfl_xor(qq, m, 64);
    if (cl == 0) red2[g][kq * 4 + reg][h] = qq;
  }
  __syncthreads();

#pragma unroll
  for (int reg = 0; reg < 4; ++reg) {
    int r16 = kq * 4 + reg;
    int row = rbase + kq * 4 + reg;
    float rnorm = 1.0f / fmaxf(sqrtf(red2[g][r16][0] + red2[g][r16][1]), 1e-12f);
    if (row < IROWS) {
      float* orow = out + (size_t)row * DIM + h * 256 + cl;
#pragma unroll
      for (int nf = 0; nf < 16; ++nf)
        orow[nf * 16] = acc[nf][reg] * rnorm;
    }
  }
}

extern "C" void kernel_launch(void* const* d_in, const int* in_sizes, int n_in,
                              void* d_out, int out_size, void* d_ws, size_t ws_size,
                              hipStream_t stream) {
  const float* zcf  = (const float*)d_in[0];
  const float* zimg = (const float*)d_in[1];
  const float* ztxt = (const float*)d_in[2];
  const float* dimg = (const float*)d_in[3];
  const float* dtxt = (const float*)d_in[4];
  const float* pa   = (const float*)d_in[5];
  const float* pb   = (const float*)d_in[6];
  const float* lnw  = (const float*)d_in[7];
  const float* lnb  = (const float*)d_in[8];
  uint16_t* bt = (uint16_t*)d_ws;   // 512*1024 bf16 = 1 MB

  hipLaunchKernelGGL(prep_bt, dim3(128), dim3(256), 0, stream, dimg, dtxt, pa, pb, bt);
  hipLaunchKernelGGL(fused_main, dim3(NBLK), dim3(THREADS), 0, stream,
                     zcf, zimg, ztxt, bt, pa, pb, lnw, lnb, (float*)d_out);
}

// Round 7
// 167.968 us; speedup vs baseline: 3.8035x; 1.2292x over previous
//
#include <hip/hip_runtime.h>
#include <cstdint>

#define IROWS 50000
#define DIM   512
#define KTOT  1024
#define THREADS 512
#define BM    64
#define NBLK ((IROWS + BM - 1) / BM)   // 782
#define NCHUNK 32
#define CK 32

typedef __bf16 bf16x8 __attribute__((ext_vector_type(8)));
typedef float  f32x4  __attribute__((ext_vector_type(4)));

// LDS layout (bytes)
#define OFF_B0 0          // B chunk buf0: 4 planes x [512 col x 16B] = 32768
#define OFF_B1 32768
#define OFF_A0 65536      // A chunk buf0: 4 planes x [64 row x 16B] = 4096
#define OFF_A1 69632
#define OFF_R1 73728      // red1[4][16][2][2] f32 = 1024
#define OFF_R2 74752      // red2[4][16][2] f32 = 512
#define SMEM_SZ 75264

__device__ __forceinline__ uint16_t f2bf(float f) {
  uint32_t u = __float_as_uint(f);
  u += 0x7fffu + ((u >> 16) & 1u);   // RNE (inputs finite)
  return (uint16_t)(u >> 16);
}

// btT layout: element (k, n) at index (k>>3)*4096 + n*8 + (k&7)
// i.e. 128 k-planes of [512 cols][8 k] bf16 — gload_lds sources are contiguous.
__global__ __launch_bounds__(256) void prep_bt(const float* __restrict__ dimg,
                                               const float* __restrict__ dtxt,
                                               const float* __restrict__ pa,
                                               const float* __restrict__ pb,
                                               uint16_t* __restrict__ btT) {
  __shared__ uint16_t tile[64][80];   // [n_local][k_local]
  int bid = blockIdx.x;               // 128 blocks: 16 k-tiles x 8 n-tiles
  int kt = bid >> 3, nt = bid & 7;
  int k0 = kt * 64, n0 = nt * 64;
  const float* src; float sc;
  if (k0 < 512) { src = dimg + (size_t)k0 * 512;         sc = pa[0]; }
  else          { src = dtxt + (size_t)(k0 - 512) * 512; sc = pb[0]; }
  int t = threadIdx.x;
  int c4 = (t & 15) * 4, r = t >> 4;
  for (int rr = r; rr < 64; rr += 16) {
    float4 v = *(const float4*)(src + (size_t)rr * 512 + n0 + c4);
    tile[c4 + 0][rr] = f2bf(v.x * sc);
    tile[c4 + 1][rr] = f2bf(v.y * sc);
    tile[c4 + 2][rr] = f2bf(v.z * sc);
    tile[c4 + 3][rr] = f2bf(v.w * sc);
  }
  __syncthreads();
  int nn = t >> 3, j8 = t & 7;
  for (int n2 = nn; n2 < 64; n2 += 32) {
    uint4 val = *(const uint4*)(&tile[n2][j8 * 8]);   // 8 consecutive k, col n2
    *(uint4*)(btT + ((size_t)((k0 >> 3) + j8)) * 4096 + (size_t)(n0 + n2) * 8) = val;
  }
}

__global__ __launch_bounds__(THREADS, 4) void fused_main(
    const float* __restrict__ zcf, const float* __restrict__ zimg,
    const float* __restrict__ ztxt, const uint16_t* __restrict__ btT,
    const float* __restrict__ pa, const float* __restrict__ pb,
    const float* __restrict__ lnw, const float* __restrict__ lnb,
    float* __restrict__ out) {
  __shared__ __align__(16) char smem[SMEM_SZ];
  const int t    = threadIdx.x;
  const int lane = t & 63;
  const int w    = t >> 6;          // 0..7
  const int g    = w >> 1;          // row-group 0..3
  const int h    = w & 1;           // col-half
  const int cl   = lane & 15;
  const int kq   = lane >> 4;       // 0..3
  const int rblk = blockIdx.x * BM;
  const int rbase = rblk + g * 16;

  f32x4 acc[16];
  const f32x4 zero = {0.f, 0.f, 0.f, 0.f};
#pragma unroll
  for (int nf = 0; nf < 16; ++nf) acc[nf] = zero;

  // ---- A path: 1 float4 per thread per chunk, depth-2 register prefetch ----
  const int ar = t >> 3;                               // 0..63 row
  const int ak = (t & 7) * 4;                          // k-offset in chunk
  const size_t arow512 = (size_t)min(rblk + ar, IROWS - 1) * DIM;
  auto aload = [&](int c) -> float4 {
    int gk = c * CK + ak;
    const float* s = (gk < 512) ? (zimg + gk) : (ztxt + gk - 512);
    return *(const float4*)(s + arow512);
  };
  const int aoff = ((t & 7) >> 1) * 1024 + ar * 16 + (t & 1) * 8;  // plane|row|half
  auto astore = [&](char* bufA, float4 v) {
    uint2 p;
    p.x = (uint32_t)f2bf(v.x) | ((uint32_t)f2bf(v.y) << 16);
    p.y = (uint32_t)f2bf(v.z) | ((uint32_t)f2bf(v.w) << 16);
    *(uint2*)(bufA + aoff) = p;
  };

  // ---- B path: 4 global_load_lds per wave per chunk (zero VGPR, 1 KB bursts) ----
  auto bstage = [&](int c, char* bufB) {
#pragma unroll
    for (int i = 0; i < 4; ++i) {
      int u = w * 4 + i;            // 0..31
      int s = u >> 3;               // k-slot plane 0..3
      int cg = u & 7;               // col-group (64 cols)
      const uint16_t* src = btT + ((size_t)(c * 4 + s)) * 4096 + cg * 512 + lane * 8;
      char* dst = bufB + s * 8192 + cg * 1024;   // wave-uniform; HW adds lane*16
      __builtin_amdgcn_global_load_lds(
          (__attribute__((address_space(1))) unsigned int*)src,
          (__attribute__((address_space(3))) unsigned int*)dst, 16, 0, 0);
    }
  };

  auto compute = [&](const char* bufB, const char* bufA) {
    bf16x8 af = *(const bf16x8*)(bufA + kq * 1024 + (g * 16 + cl) * 16);
#pragma unroll
    for (int nf = 0; nf < 16; ++nf) {
      int n = h * 256 + nf * 16 + cl;
      bf16x8 bf = *(const bf16x8*)(bufB + kq * 8192 + n * 16);
      acc[nf] = __builtin_amdgcn_mfma_f32_16x16x32_bf16(af, bf, acc[nf], 0, 0, 0);
    }
  };

  char* B0 = smem + OFF_B0; char* B1 = smem + OFF_B1;
  char* A0 = smem + OFF_A0; char* A1 = smem + OFF_A1;

  // ---- prologue ----
  float4 Av = aload(0);
  bstage(0, B0);
  float4 S1 = aload(1);
  float4 S0 = aload(2);
  asm volatile("s_waitcnt vmcnt(2)" ::: "memory");   // Av + B(0) done; S1,S0 fly
  __builtin_amdgcn_sched_barrier(0);
  astore(A0, Av);
  asm volatile("s_waitcnt lgkmcnt(0)" ::: "memory");
  __builtin_amdgcn_sched_barrier(0);
  __builtin_amdgcn_s_barrier();
  __builtin_amdgcn_sched_barrier(0);

  // body: stage(c+1)->nxt, write A(c+1) from S, reload S=A(c+3), compute(c),
  // counted vmcnt(1) keeps the newest A-load flying across the barrier.
#define BODY(c, curB, curA, nxtB, nxtA, S)                                   \
  {                                                                          \
    bstage((c) + 1, nxtB);                                                   \
    astore(nxtA, S);                                                         \
    S = aload(((c) + 3 < NCHUNK) ? (c) + 3 : NCHUNK - 1);                    \
    __builtin_amdgcn_sched_barrier(0);                                       \
    compute(curB, curA);                                                     \
    asm volatile("s_waitcnt vmcnt(1)" ::: "memory");                         \
    asm volatile("s_waitcnt lgkmcnt(0)" ::: "memory");                       \
    __builtin_amdgcn_sched_barrier(0);                                       \
    __builtin_amdgcn_s_barrier();                                            \
    __builtin_amdgcn_sched_barrier(0);                                       \
  }

#pragma unroll 1
  for (int c = 0; c < NCHUNK - 2; c += 2) {
    BODY(c,     B0, A0, B1, A1, S1)
    BODY(c + 1, B1, A1, B0, A0, S0)
  }
  // c = 30 handled by loop (NCHUNK-2=30 exclusive → last loop iter c=28 covers 28,29)
  BODY(NCHUNK - 2, B0, A0, B1, A1, S1)   // c=30: stages chunk 31
  compute(B1, A1);                       // c=31
#undef BODY

  // ---- epilogue: + wcf*z_cf, LayerNorm, L2 normalize (R6-verified) ----
  const float wcf = 1.0f - pa[0] - pb[0];
  float (*red1)[16][2][2] = (float (*)[16][2][2])(smem + OFF_R1);
  float (*red2)[16][2]    = (float (*)[16][2])(smem + OFF_R2);

#pragma unroll
  for (int nf = 0; nf < 16; ++nf) {
#pragma unroll
    for (int reg = 0; reg < 4; ++reg) {
      int row = min(rbase + kq * 4 + reg, IROWS - 1);
      acc[nf][reg] += wcf * zcf[(size_t)row * DIM + h * 256 + nf * 16 + cl];
    }
  }

#pragma unroll
  for (int reg = 0; reg < 4; ++reg) {
    float s1 = 0.f, s2 = 0.f;
#pragma unroll
    for (int nf = 0; nf < 16; ++nf) { float v = acc[nf][reg]; s1 += v; s2 += v * v; }
#pragma unroll
    for (int m = 1; m < 16; m <<= 1) { s1 += __shfl_xor(s1, m, 64); s2 += __shfl_xor(s2, m, 64); }
    if (cl == 0) {
      red1[g][kq * 4 + reg][h][0] = s1;
      red1[g][kq * 4 + reg][h][1] = s2;
    }
  }
  __syncthreads();
  float mu[4], rs[4];
#pragma unroll
  for (int reg = 0; reg < 4; ++reg) {
    int r16 = kq * 4 + reg;
    float s1 = red1[g][r16][0][0] + red1[g][r16][1][0];
    float s2 = red1[g][r16][0][1] + red1[g][r16][1][1];
    float mean = s1 * (1.0f / 512.0f);
    mu[reg] = mean;
    rs[reg] = rsqrtf(s2 * (1.0f / 512.0f) - mean * mean + 1e-5f);
  }

  float q[4] = {0.f, 0.f, 0.f, 0.f};
#pragma unroll
  for (int nf = 0; nf < 16; ++nf) {
    int col = h * 256 + nf * 16 + cl;
    float wv = lnw[col];
    float bv = lnb[col];
#pragma unroll
    for (int reg = 0; reg < 4; ++reg) {
      float y = (acc[nf][reg] - mu[reg]) * rs[reg] * wv + bv;
      acc[nf][reg] = y;
      q[reg] += y * y;
    }
  }
#pragma unroll
  for (int reg = 0; reg < 4; ++reg) {
    float qq = q[reg];
#pragma unroll
    for (int m = 1; m < 16; m <<= 1) qq += __shfl_xor(qq, m, 64);
    if (cl == 0) red2[g][kq * 4 + reg][h] = qq;
  }
  __syncthreads();

#pragma unroll
  for (int reg = 0; reg < 4; ++reg) {
    int r16 = kq * 4 + reg;
    int row = rbase + kq * 4 + reg;
    float rnorm = 1.0f / fmaxf(sqrtf(red2[g][r16][0] + red2[g][r16][1]), 1e-12f);
    if (row < IROWS) {
      float* orow = out + (size_t)row * DIM + h * 256 + cl;
#pragma unroll
      for (int nf = 0; nf < 16; ++nf)
        orow[nf * 16] = acc[nf][reg] * rnorm;
    }
  }
}

extern "C" void kernel_launch(void* const* d_in, const int* in_sizes, int n_in,
                              void* d_out, int out_size, void* d_ws, size_t ws_size,
                              hipStream_t stream) {
  const float* zcf  = (const float*)d_in[0];
  const float* zimg = (const float*)d_in[1];
  const float* ztxt = (const float*)d_in[2];
  const float* dimg = (const float*)d_in[3];
  const float* dtxt = (const float*)d_in[4];
  const float* pa   = (const float*)d_in[5];
  const float* pb   = (const float*)d_in[6];
  const float* lnw  = (const float*)d_in[7];
  const float* lnb  = (const float*)d_in[8];
  uint16_t* btT = (uint16_t*)d_ws;   // 1 MB, k-plane-major bf16

  hipLaunchKernelGGL(prep_bt, dim3(128), dim3(256), 0, stream, dimg, dtxt, pa, pb, btT);
  hipLaunchKernelGGL(fused_main, dim3(NBLK), dim3(THREADS), 0, stream,
                     zcf, zimg, ztxt, btT, pa, pb, lnw, lnb, (float*)d_out);
}